// Round 3
// baseline (184019.507 us; speedup 1.0000x reference)
//
#include <hip/hip_runtime.h>

typedef unsigned int uint;
typedef unsigned short u16;
typedef __bf16 bf16x8 __attribute__((ext_vector_type(8)));
typedef float f32x16 __attribute__((ext_vector_type(16)));

__device__ __forceinline__ u16 f2bf(float f) {
  uint u = __builtin_bit_cast(uint, f);
  u = (u + 0x7fffu + ((u >> 16) & 1u)) >> 16;
  return (u16)u;
}
__device__ __forceinline__ float bf2f(u16 h) {
  uint u = ((uint)h) << 16;
  return __builtin_bit_cast(float, u);
}
__device__ __forceinline__ float ftanh(float x) {
  float e = __builtin_amdgcn_exp2f(x * 2.885390082f);
  return 1.0f - 2.0f * __builtin_amdgcn_rcpf(e + 1.0f);
}

// ---------- sentinel: encode diagnostics into absmax ----------
extern "C" __global__ void sent_k(float* out, float val, int n) {
  int i = blockIdx.x * 256 + threadIdx.x;
  if (i < n) out[i] = val;
}

// ---------- simple fp32 RNN step (layers 0..62), obviously correct ----------
// grid 256: b = bid>>2 (64 batches), quarter = bid&3 (128 j each)
// wave w handles j = quarter*128 + w*32 + jj, lanes cover k, shuffle-reduce.
extern "C" __global__ void __launch_bounds__(256)
step_k(const float* __restrict__ xin_t, const float* __restrict__ Wih_l,
       const float* __restrict__ Whh_l, const float* __restrict__ bih_l,
       const float* __restrict__ bhh_l, const float* __restrict__ hprev,
       float* __restrict__ hcur, float* __restrict__ seqout_t, int use_h) {
  __shared__ float xr[512], hr[512];
  const int tid = threadIdx.x;
  const int b = blockIdx.x >> 2, quarter = blockIdx.x & 3;
  xr[tid] = xin_t[b * 512 + tid];
  xr[tid + 256] = xin_t[b * 512 + 256 + tid];
  if (use_h) {
    hr[tid] = hprev[b * 512 + tid];
    hr[tid + 256] = hprev[b * 512 + 256 + tid];
  }
  __syncthreads();
  const int wv = tid >> 6, lane = tid & 63;
#pragma unroll 1
  for (int jj = 0; jj < 32; ++jj) {
    const int j = quarter * 128 + wv * 32 + jj;
    const float* wr = Wih_l + (size_t)j * 512;
    float p = 0.f;
#pragma unroll
    for (int i = 0; i < 8; ++i) p += xr[i * 64 + lane] * wr[i * 64 + lane];
    if (use_h) {
      const float* wh = Whh_l + (size_t)j * 512;
#pragma unroll
      for (int i = 0; i < 8; ++i) p += hr[i * 64 + lane] * wh[i * 64 + lane];
    }
#pragma unroll
    for (int off = 32; off; off >>= 1) p += __shfl_down(p, off, 64);
    if (lane == 0) {
      float v = tanhf(p + bih_l[j] + bhh_l[j]);
      hcur[b * 512 + j] = v;
      seqout_t[b * 512 + j] = v;
    }
  }
}

// ---------- MFMA step (layer 63 only): verbatim machinery under test ----------
// grid 4 blocks (q = out-col chunk of 128), 256 thr. A=[xin;h] in LDS, XOR-swizzled.
// h buffers: 4 chunks x [64][128] bf16 (chunk stride 8192 elems).
extern "C" __global__ void __launch_bounds__(256, 1)
mfma_step(const float* __restrict__ xin_t, const float* __restrict__ Wih_l,
          const float* __restrict__ Whh_l, const float* __restrict__ bih_l,
          const float* __restrict__ bhh_l, const u16* __restrict__ hprev,
          u16* __restrict__ hcur, int use_h) {
  extern __shared__ char smem[];
  const int tid = threadIdx.x, q = blockIdx.x;
  const int wv = tid >> 6, lane = tid & 63, l31 = lane & 31, lh = lane >> 5;

  const int jc = q * 128 + wv * 32 + l31;
  const float* wih_row = Wih_l + (size_t)jc * 512;
  const float* whh_row = Whh_l + (size_t)jc * 512;
  bf16x8 Bf[64];
#pragma unroll
  for (int s = 0; s < 64; ++s) {
    const int k = s * 16 + lh * 8;
    const float* src = (s < 32) ? (wih_row + k) : (whh_row + (k - 512));
    float4 f0 = *(const float4*)src;
    float4 f1 = *(const float4*)(src + 4);
    union { u16 us[8]; bf16x8 v; } u;
    u.us[0] = f2bf(f0.x); u.us[1] = f2bf(f0.y); u.us[2] = f2bf(f0.z); u.us[3] = f2bf(f0.w);
    u.us[4] = f2bf(f1.x); u.us[5] = f2bf(f1.y); u.us[6] = f2bf(f1.z); u.us[7] = f2bf(f1.w);
    Bf[s] = u.v;
  }
  const float bias = bih_l[jc] + bhh_l[jc];

  int abase[2][4];
#pragma unroll
  for (int m = 0; m < 2; ++m) {
    const int row = m * 32 + l31;
    const int swz = (row & 7) << 4;
#pragma unroll
    for (int c = 0; c < 4; ++c) abase[m][c] = row * 2048 + ((c * 32 + lh * 16) ^ swz);
  }

  // stage xin (fp32 -> bf16) into A cols [0,512)
#pragma unroll
  for (int i = 0; i < 16; ++i) {
    const int v = tid + (i << 8);
    const int qp = v >> 10, e = v & 1023, b = e >> 4, j8 = (e & 15) << 3;
    const int k = qp * 128 + j8;
    const int doff = b * 2048 + ((k * 2) ^ ((b & 7) << 4));
    const float* src = xin_t + (size_t)b * 512 + k;
    float4 f0 = *(const float4*)src;
    float4 f1 = *(const float4*)(src + 4);
    union { u16 us[8]; uint4 v4; } u;
    u.us[0] = f2bf(f0.x); u.us[1] = f2bf(f0.y); u.us[2] = f2bf(f0.z); u.us[3] = f2bf(f0.w);
    u.us[4] = f2bf(f1.x); u.us[5] = f2bf(f1.y); u.us[6] = f2bf(f1.z); u.us[7] = f2bf(f1.w);
    *(uint4*)(smem + doff) = u.v4;
  }
  // stage h_prev (bf16) into A cols [512,1024)
#pragma unroll
  for (int i = 0; i < 16; ++i) {
    const int v = tid + (i << 8);
    const int qp = v >> 10, e = v & 1023, b = e >> 4, j8 = (e & 15) << 3;
    const int k = 512 + qp * 128 + j8;
    const int doff = b * 2048 + ((k * 2) ^ ((b & 7) << 4));
    uint4 val = make_uint4(0, 0, 0, 0);
    if (use_h) val = *(const uint4*)(hprev + qp * 8192 + b * 128 + j8);
    *(uint4*)(smem + doff) = val;
  }
  __syncthreads();

  f32x16 acc0 = {};
  f32x16 acc1 = {};
#pragma unroll
  for (int s = 0; s < 64; ++s) {
    const bf16x8 a0 = *(const bf16x8*)(smem + abase[0][s & 3] + ((s >> 2) << 7));
    const bf16x8 a1 = *(const bf16x8*)(smem + abase[1][s & 3] + ((s >> 2) << 7));
    acc0 = __builtin_amdgcn_mfma_f32_32x32x16_bf16(a0, Bf[s], acc0, 0, 0, 0);
    acc1 = __builtin_amdgcn_mfma_f32_32x32x16_bf16(a1, Bf[s], acc1, 0, 0, 0);
  }

  u16* dst = hcur + q * 8192 + wv * 32 + l31;
#pragma unroll
  for (int m = 0; m < 2; ++m) {
#pragma unroll
    for (int r = 0; r < 16; ++r) {
      const int row = m * 32 + (r & 3) + ((r >> 2) << 3) + (lh << 2);
      const float v = (m ? acc1[r] : acc0[r]) + bias;
      dst[row * 128] = f2bf(ftanh(v));
    }
  }
}

// ---------- head: out[b][j] = lb[j] + sum_k h[b][k] * lw[j][k] ----------
extern "C" __global__ void __launch_bounds__(512)
head2(const u16* __restrict__ hfin, const float* __restrict__ lw,
      const float* __restrict__ lb, float* __restrict__ out) {
  __shared__ float hrow[512];
  const int b = blockIdx.x, j = threadIdx.x;
  hrow[j] = bf2f(hfin[(j >> 7) * 8192 + b * 128 + (j & 127)]);
  __syncthreads();
  const float* wrow = lw + (size_t)j * 512;
  float s = lb[j];
#pragma unroll 4
  for (int k = 0; k < 512; k += 4) {
    const float4 w = *(const float4*)(wrow + k);
    s += hrow[k] * w.x + hrow[k + 1] * w.y + hrow[k + 2] * w.z + hrow[k + 3] * w.w;
  }
  out[(size_t)b * 512 + j] = s;
}

extern "C" void kernel_launch(void* const* d_in, const int* in_sizes, int n_in,
                              void* d_out, int out_size, void* d_ws, size_t ws_size,
                              hipStream_t stream) {
  const float* x   = (const float*)d_in[0];
  const float* Wih = (const float*)d_in[1];
  const float* Whh = (const float*)d_in[2];
  const float* bih = (const float*)d_in[3];
  const float* bhh = (const float*)d_in[4];
  const float* lw  = (const float*)d_in[5];
  const float* lb  = (const float*)d_in[6];
  float* out = (float*)d_out;

  const bool ok = n_in == 7 && in_sizes[0] == 4194304 && in_sizes[1] == 16777216 &&
                  in_sizes[2] == 16777216 && in_sizes[3] == 32768 && in_sizes[4] == 32768 &&
                  in_sizes[5] == 262144 && in_sizes[6] == 512 && out_size == 32768;
  if (!ok) {  // sentinel: convention mismatch
    sent_k<<<128, 256, 0, stream>>>(out, 900.0f, out_size);
    return;
  }
  // ws layout: hA f32 128K | hB f32 128K | hbfA 64K | hbfB 64K | pad | seqA 16M | seqB 16M
  float* hA = (float*)d_ws;
  float* hB = (float*)((char*)d_ws + 131072);
  u16* hbfA = (u16*)((char*)d_ws + 262144);
  u16* hbfB = (u16*)((char*)d_ws + 327680);
  float* seqA = (float*)((char*)d_ws + 524288);
  float* seqB = (float*)((char*)d_ws + 524288 + 16777216);
  const size_t need = 524288 + 2ull * 16777216;
  if (ws_size < need) {  // sentinel: decode ws MB from absmax
    sent_k<<<128, 256, 0, stream>>>(out, 100.0f + (float)(ws_size >> 20), out_size);
    return;
  }

  // layers 0..62: simple fp32 path, layer-serial, seq ping-pong
  for (int l = 0; l < 63; ++l) {
    const float* in_l = (l == 0) ? x : ((l & 1) ? seqA : seqB);
    float* out_l = (l & 1) ? seqB : seqA;
    const float* Wi = Wih + (size_t)l * 262144;
    const float* Wh = Whh + (size_t)l * 262144;
    const float* bi = bih + l * 512;
    const float* bh = bhh + l * 512;
    for (int t = 0; t < 128; ++t) {
      float* hc = (t & 1) ? hB : hA;
      const float* hp = (t & 1) ? hA : hB;
      step_k<<<256, 256, 0, stream>>>(in_l + (size_t)t * 32768, Wi, Wh, bi, bh,
                                      hp, hc, out_l + (size_t)t * 32768, t > 0 ? 1 : 0);
    }
  }
  // layer 63: MFMA machinery under test (layer 62 output = seqA)
  hipFuncSetAttribute((const void*)mfma_step,
                      hipFuncAttributeMaxDynamicSharedMemorySize, 131072);
  {
    const int l = 63;
    const float* Wi = Wih + (size_t)l * 262144;
    const float* Wh = Whh + (size_t)l * 262144;
    const float* bi = bih + l * 512;
    const float* bh = bhh + l * 512;
    for (int t = 0; t < 128; ++t) {
      u16* hc = (t & 1) ? hbfB : hbfA;
      const u16* hp = (t & 1) ? hbfA : hbfB;
      mfma_step<<<4, 256, 131072, stream>>>(seqA + (size_t)t * 32768, Wi, Wh, bi, bh,
                                            hp, hc, t > 0 ? 1 : 0);
    }
  }
  head2<<<64, 512, 0, stream>>>(hbfB, lw, lb, out);  // t=127 odd -> hbfB
}

// Round 5
// 106828.503 us; speedup vs baseline: 1.7226x; 1.7226x over previous
//
#include <hip/hip_runtime.h>

#define TSTEPS 128
#define NB 64
#define HD 512
#define NLAYER 64
#define RSLOT 4
#define RMASK 3
#define SPIN_CAP 120000

typedef unsigned int uint;

// ring slot: [layer][slot] of 64x512 fp32 (32768 floats = 128KB)
__device__ __forceinline__ size_t ringOff(int layer, int slot) {
  return ((size_t)(layer * RSLOT + slot)) << 15;
}

extern "C" __global__ void sent_k(float* out, float val, int n) {
  int i = blockIdx.x * 256 + threadIdx.x;
  if (i < n) out[i] = val;
}

// fp32 VALU systolic: 64 layer-groups x 4 CUs, identical protocol to round 4.
// Per block: out cols [128q,128q+128), M=64 rows, K=1024 ([x 512 | h 512]).
// Lane owns row b=lane; wave owns 32 cols; W rows streamed (wave-uniform).
extern "C" __global__ void __launch_bounds__(256)
rnn_pipe(const float* __restrict__ x, const float* __restrict__ Wih,
         const float* __restrict__ Whh, const float* __restrict__ bih,
         const float* __restrict__ bhh, float* ring, uint* prod, uint* cons,
         uint* eflag) {
  __shared__ float cbuf[64][129];
  const int tid = threadIdx.x;
  const int bid = blockIdx.x;
  const int slotid = ((bid & 7) << 5) | (bid >> 3);  // XCD-grouped layers
  const int layer = slotid >> 2;
  const int q = slotid & 3;
  const int wv = tid >> 6;
  const int lane = tid & 63;

  const float* wih_base = Wih + ((size_t)layer * HD + q * 128 + wv * 32) * HD;
  const float* whh_base = Whh + ((size_t)layer * HD + q * 128 + wv * 32) * HD;
  const int jb = layer * HD + q * 128 + wv * 32;

  int cap = SPIN_CAP;

#pragma unroll 1
  for (int t = 0; t < TSTEPS; ++t) {
    const int sT = t & RMASK;
    const int sP = (t - 1) & RMASK;
    if (tid == 0) {
      uint code = 0;
      if (layer < NLAYER - 1 && t >= RSLOT) {
        const uint need = 4u * (uint)(t - RSLOT + 1);
        int sp = 0;
        while (__hip_atomic_load(&cons[layer], __ATOMIC_ACQUIRE, __HIP_MEMORY_SCOPE_AGENT) < need) {
          __builtin_amdgcn_s_sleep(2);
          if (++sp > cap) { code = 1000u + layer; break; }
        }
      }
      if (layer > 0) {
        const uint need = 4u * (uint)(t + 1);
        int sp = 0;
        while (__hip_atomic_load(&prod[layer - 1], __ATOMIC_ACQUIRE, __HIP_MEMORY_SCOPE_AGENT) < need) {
          __builtin_amdgcn_s_sleep(2);
          if (++sp > cap) { code = 3000u + layer; break; }
        }
      }
      if (t > 0) {
        const uint need = 4u * (uint)t;
        int sp = 0;
        while (__hip_atomic_load(&prod[layer], __ATOMIC_ACQUIRE, __HIP_MEMORY_SCOPE_AGENT) < need) {
          __builtin_amdgcn_s_sleep(2);
          if (++sp > cap) { code = 5000u + layer; break; }
        }
      }
      if (code) {
        __hip_atomic_fetch_max(eflag, code, __ATOMIC_RELAXED, __HIP_MEMORY_SCOPE_AGENT);
        cap = 2000;
      }
    }
    __syncthreads();
    __builtin_amdgcn_fence(__ATOMIC_ACQUIRE, "agent");

    float acc[32];
#pragma unroll
    for (int j = 0; j < 32; ++j) acc[j] = 0.f;

    // ---- pass 0: x-path (prev-layer ring or input x), K=512 ----
    {
      const float* arow = (layer == 0)
                              ? x + ((size_t)t * NB + lane) * HD
                              : ring + ringOff(layer - 1, sT) + (size_t)lane * HD;
#pragma unroll 1
      for (int c = 0; c < 8; ++c) {
        float4 a[16];
#pragma unroll
        for (int i = 0; i < 16; ++i) a[i] = *(const float4*)(arow + c * 64 + i * 4);
#pragma unroll
        for (int j = 0; j < 32; ++j) {
          const float4* w = (const float4*)(wih_base + (size_t)j * HD + c * 64);
#pragma unroll
          for (int i = 0; i < 16; ++i) {
            const float4 wv4 = w[i];
            acc[j] += a[i].x * wv4.x + a[i].y * wv4.y + a[i].z * wv4.z + a[i].w * wv4.w;
          }
        }
      }
    }
    // ---- pass 1: h-path (own-layer ring), K=512 ----
    if (t > 0) {
      const float* arow = ring + ringOff(layer, sP) + (size_t)lane * HD;
#pragma unroll 1
      for (int c = 0; c < 8; ++c) {
        float4 a[16];
#pragma unroll
        for (int i = 0; i < 16; ++i) a[i] = *(const float4*)(arow + c * 64 + i * 4);
#pragma unroll
        for (int j = 0; j < 32; ++j) {
          const float4* w = (const float4*)(whh_base + (size_t)j * HD + c * 64);
#pragma unroll
          for (int i = 0; i < 16; ++i) {
            const float4 wv4 = w[i];
            acc[j] += a[i].x * wv4.x + a[i].y * wv4.y + a[i].z * wv4.z + a[i].w * wv4.w;
          }
        }
      }
    }
    __syncthreads();  // all ring reads of this step complete
    if (tid == 0 && layer > 0)
      __hip_atomic_fetch_add(&cons[layer - 1], 1u, __ATOMIC_RELEASE, __HIP_MEMORY_SCOPE_AGENT);

    // ---- epilogue: bias + tanh -> cbuf transpose -> ring store ----
#pragma unroll
    for (int j = 0; j < 32; ++j)
      cbuf[lane][wv * 32 + j] = tanhf(acc[j] + bih[jb + j] + bhh[jb + j]);
    __syncthreads();
    {
      float* dst = ring + ringOff(layer, sT);
#pragma unroll
      for (int i = 0; i < 32; ++i) {
        const int idx = tid + (i << 8);
        const int b = idx >> 7, c = idx & 127;
        dst[(size_t)b * HD + q * 128 + c] = cbuf[b][c];
      }
    }
    __builtin_amdgcn_fence(__ATOMIC_RELEASE, "agent");
    __syncthreads();
    if (tid == 0)
      __hip_atomic_fetch_add(&prod[layer], 1u, __ATOMIC_RELEASE, __HIP_MEMORY_SCOPE_AGENT);
  }
}

// out[b][j] = lb[j] + sum_k h_last[b][k] * lw[j][k]  (+ eflag sentinel on out[0])
extern "C" __global__ void __launch_bounds__(512)
head_k(const float* __restrict__ ring, const float* __restrict__ lw,
       const float* __restrict__ lb, float* __restrict__ out,
       const uint* __restrict__ eflag) {
  __shared__ float hrow[HD];
  const int b = blockIdx.x;
  const int j = threadIdx.x;
  hrow[j] = ring[ringOff(NLAYER - 1, (TSTEPS - 1) & RMASK) + (size_t)b * HD + j];
  __syncthreads();
  const float* wrow = lw + (size_t)j * HD;
  float s = lb[j];
#pragma unroll 4
  for (int k = 0; k < HD; k += 4) {
    const float4 w = *(const float4*)(wrow + k);
    s += hrow[k] * w.x + hrow[k + 1] * w.y + hrow[k + 2] * w.z + hrow[k + 3] * w.w;
  }
  if (b == 0 && j == 0) s += (float)eflag[0];
  out[(size_t)b * HD + j] = s;
}

extern "C" void kernel_launch(void* const* d_in, const int* in_sizes, int n_in,
                              void* d_out, int out_size, void* d_ws, size_t ws_size,
                              hipStream_t stream) {
  const float* x   = (const float*)d_in[0];
  const float* Wih = (const float*)d_in[1];
  const float* Whh = (const float*)d_in[2];
  const float* bih = (const float*)d_in[3];
  const float* bhh = (const float*)d_in[4];
  const float* lw  = (const float*)d_in[5];
  const float* lb  = (const float*)d_in[6];
  float* out = (float*)d_out;

  const bool ok = n_in == 7 && in_sizes[0] == 4194304 && in_sizes[1] == 16777216 &&
                  in_sizes[2] == 16777216 && in_sizes[3] == 32768 && in_sizes[4] == 32768 &&
                  in_sizes[5] == 262144 && in_sizes[6] == 512 && out_size == 32768;
  const size_t need = 4096 + (size_t)NLAYER * RSLOT * 32768 * 4;  // 33.5 MB
  if (!ok || ws_size < need) {
    sent_k<<<128, 256, 0, stream>>>(out, ok ? (100.0f + (float)(ws_size >> 20)) : 900.0f,
                                    out_size);
    return;
  }

  uint* prod = (uint*)d_ws;
  uint* cons = prod + 64;
  uint* eflag = cons + 64;
  float* ring = (float*)((char*)d_ws + 4096);

  hipMemsetAsync(d_ws, 0, 4096, stream);
  rnn_pipe<<<256, 256, 0, stream>>>(x, Wih, Whh, bih, bhh, ring, prod, cons, eflag);
  head_k<<<64, 512, 0, stream>>>(ring, lw, lb, out, eflag);
}

// Round 6
// 18914.143 us; speedup vs baseline: 9.7292x; 5.6481x over previous
//
#include <hip/hip_runtime.h>

#define TSTEPS 128
#define NB 64
#define HD 512
#define LPP 32        // layers per pass (2 passes)
#define RSLOT 4
#define RMASK 3
#define SPIN_CAP 120000

typedef unsigned int uint;
typedef unsigned long long ull;
typedef _Float16 f16;
typedef _Float16 f16x8 __attribute__((ext_vector_type(8)));
typedef float f32x16 __attribute__((ext_vector_type(16)));

// ring slot: [layer 0..31][slot 0..3] of 64x512 fp32 (32768 floats = 128KB)
__device__ __forceinline__ size_t ringOff(int layer, int slot) {
  return ((size_t)(layer * RSLOT + slot)) << 15;
}

extern "C" __global__ void sent_k(float* out, float val, int n) {
  int i = blockIdx.x * 256 + threadIdx.x;
  if (i < n) out[i] = val;
}

// 32 layer-groups x 8 CUs (one XCD holds 4 layers). Per CU: 64 out-cols, M=64, K=1024.
// W f16 hi/lo resident in VGPRs (4 waves = kh x nh; 256 W-regs/lane).
// A=[x | h] staged per-half as f16 hi/lo in LDS (2x64KB), XOR-swizzled.
// 3-term MFMA: Ah*Wh + Al*Wh + Ah*Wl  (~fp23 precision). Ring stays fp32.
extern "C" __global__ void __launch_bounds__(256, 1)
rnn_pipe(const float* __restrict__ xin, const float* __restrict__ Wih,
         const float* __restrict__ Whh, const float* __restrict__ bih,
         const float* __restrict__ bhh, float* ring, float* seqout,
         uint* prod, uint* cons, uint* eflag) {
  extern __shared__ char smem[];  // A_hi @0 (64KB), A_lo @65536 (64KB); scr overlays @0
  const int tid = threadIdx.x;
  const int bid = blockIdx.x;
  const int slotid = ((bid & 7) << 5) | (bid >> 3);  // 32 consecutive slots per XCD
  const int layer = slotid >> 3;                     // 4 layers per XCD
  const int c8 = slotid & 7;                         // col-eighth (64 cols)
  const int wv = tid >> 6;
  const int lane = tid & 63;
  const int l31 = lane & 31;
  const int lh = lane >> 5;       // k-half within a 16-k MFMA step
  const int kh = wv >> 1;         // K-quarter pair: this wave's 256-k slice of each half
  const int nh = wv & 1;          // col-half (32 cols)
  const int jc = c8 * 64 + nh * 32 + l31;

  // ---- weights -> VGPRs as f16 hi/lo (once) ----
  const float* wih_row = Wih + ((size_t)layer * HD + jc) * HD + kh * 256;
  const float* whh_row = Whh + ((size_t)layer * HD + jc) * HD + kh * 256;
  f16x8 WihH[16], WihL[16], WhhH[16], WhhL[16];
#pragma unroll
  for (int s = 0; s < 16; ++s) {
    const int k = s * 16 + lh * 8;
#pragma unroll
    for (int p = 0; p < 2; ++p) {
      const float* src = p ? (whh_row + k) : (wih_row + k);
      float4 f0 = *(const float4*)src;
      float4 f1 = *(const float4*)(src + 4);
      union { f16 h[8]; f16x8 v; } H, L;
      float c[8] = {f0.x, f0.y, f0.z, f0.w, f1.x, f1.y, f1.z, f1.w};
#pragma unroll
      for (int e = 0; e < 8; ++e) {
        f16 hv = (f16)c[e];
        H.h[e] = hv;
        L.h[e] = (f16)(c[e] - (float)hv);
      }
      if (p) { WhhH[s] = H.v; WhhL[s] = L.v; }
      else   { WihH[s] = H.v; WihL[s] = L.v; }
    }
  }
  const float bias = bih[layer * HD + jc] + bhh[layer * HD + jc];

  const int rswz = (l31 & 7) << 4;
  const int rowoff0 = l31 * 1024;
  const int rowoff1 = (32 + l31) * 1024;
  const int khb = kh * 512;       // byte base of this wave's k-slice within a half
  const int lh16 = lh * 16;

  int cap = SPIN_CAP;

#pragma unroll 1
  for (int t = 0; t < TSTEPS; ++t) {
    const int sT = t & RMASK;
    const int sP = (t - 1) & RMASK;
    // ---- waits (tid 0; block-uniform) ----
    if (tid == 0) {
      uint code = 0;
      if (layer < LPP - 1 && t >= RSLOT) {
        const uint need = 8u * (uint)(t - RSLOT + 1);
        int sp = 0;
        while (__hip_atomic_load(&cons[layer], __ATOMIC_ACQUIRE, __HIP_MEMORY_SCOPE_AGENT) < need) {
          __builtin_amdgcn_s_sleep(2);
          if (++sp > cap) { code = 1000u + layer; break; }
        }
      }
      if (layer > 0) {
        const uint need = 8u * (uint)(t + 1);
        int sp = 0;
        while (__hip_atomic_load(&prod[layer - 1], __ATOMIC_ACQUIRE, __HIP_MEMORY_SCOPE_AGENT) < need) {
          __builtin_amdgcn_s_sleep(2);
          if (++sp > cap) { code = 3000u + layer; break; }
        }
      }
      if (t > 0) {
        const uint need = 8u * (uint)t;
        int sp = 0;
        while (__hip_atomic_load(&prod[layer], __ATOMIC_ACQUIRE, __HIP_MEMORY_SCOPE_AGENT) < need) {
          __builtin_amdgcn_s_sleep(2);
          if (++sp > cap) { code = 5000u + layer; break; }
        }
      }
      if (code) {
        __hip_atomic_fetch_max(eflag, code, __ATOMIC_RELAXED, __HIP_MEMORY_SCOPE_AGENT);
        cap = 2000;
      }
    }
    __syncthreads();
    __builtin_amdgcn_fence(__ATOMIC_ACQUIRE, "agent");

    f32x16 acc0 = {};
    f32x16 acc1 = {};

    // ---- stage a 512-K half: fp32 src -> f16 hi/lo in LDS (swizzled) ----
    auto stage = [&](const float* src) {
#pragma unroll 4
      for (int i = 0; i < 32; ++i) {
        const int idx4 = tid + (i << 8);          // [0,8192)
        const int b = idx4 >> 7, k4 = idx4 & 127;
        float4 v = src ? ((const float4*)src)[(size_t)b * 128 + k4]
                       : make_float4(0.f, 0.f, 0.f, 0.f);
        union { f16 h[4]; ull u; } H, L;
        float c[4] = {v.x, v.y, v.z, v.w};
#pragma unroll
        for (int e = 0; e < 4; ++e) {
          f16 hv = (f16)c[e];
          H.h[e] = hv;
          L.h[e] = (f16)(c[e] - (float)hv);
        }
        const int off = b * 1024 + ((k4 * 8) ^ ((b & 7) << 4));
        *(ull*)(smem + off) = H.u;
        *(ull*)(smem + 65536 + off) = L.u;
      }
    };
    // ---- 3-term MFMA over this wave's 256-K slice of the staged half ----
    auto compute = [&](const f16x8* WH, const f16x8* WL) {
#pragma unroll
      for (int s = 0; s < 16; ++s) {
        const int kb = khb + s * 32 + lh16;
#pragma unroll
        for (int mt = 0; mt < 2; ++mt) {
          const int off = (mt ? rowoff1 : rowoff0) + (kb ^ rswz);
          const f16x8 ah = *(const f16x8*)(smem + off);
          const f16x8 al = *(const f16x8*)(smem + 65536 + off);
          if (mt == 0) {
            acc0 = __builtin_amdgcn_mfma_f32_32x32x16_f16(ah, WH[s], acc0, 0, 0, 0);
            acc0 = __builtin_amdgcn_mfma_f32_32x32x16_f16(al, WH[s], acc0, 0, 0, 0);
            acc0 = __builtin_amdgcn_mfma_f32_32x32x16_f16(ah, WL[s], acc0, 0, 0, 0);
          } else {
            acc1 = __builtin_amdgcn_mfma_f32_32x32x16_f16(ah, WH[s], acc1, 0, 0, 0);
            acc1 = __builtin_amdgcn_mfma_f32_32x32x16_f16(al, WH[s], acc1, 0, 0, 0);
            acc1 = __builtin_amdgcn_mfma_f32_32x32x16_f16(ah, WL[s], acc1, 0, 0, 0);
          }
        }
      }
    };

    // half 1: x-path
    stage(layer == 0 ? xin + (size_t)t * 32768 : ring + ringOff(layer - 1, sT));
    __syncthreads();
    if (tid == 0 && layer > 0)
      __hip_atomic_fetch_add(&cons[layer - 1], 1u, __ATOMIC_RELEASE, __HIP_MEMORY_SCOPE_AGENT);
    compute(WihH, WihL);
    __syncthreads();
    // half 2: h-path
    stage(t > 0 ? ring + ringOff(layer, sP) : nullptr);
    __syncthreads();
    compute(WhhH, WhhL);
    __syncthreads();

    // ---- cross-wave K-reduction (scratch overlays A_hi region) ----
    float* scr = (float*)smem;
    if (kh == 1) {
#pragma unroll
      for (int mt = 0; mt < 2; ++mt)
#pragma unroll
        for (int r = 0; r < 16; ++r)
          scr[(nh * 2 + mt) * 1024 + lane * 16 + r] = (mt ? acc1 : acc0)[r];
    }
    __syncthreads();
    if (kh == 0) {
      float* dst = ring + ringOff(layer, sT);
      float* sq = (seqout && layer == LPP - 1) ? seqout + (size_t)t * 32768 : nullptr;
#pragma unroll
      for (int mt = 0; mt < 2; ++mt)
#pragma unroll
        for (int r = 0; r < 16; ++r) {
          float v = (mt ? acc1 : acc0)[r] + scr[(nh * 2 + mt) * 1024 + lane * 16 + r];
          v = tanhf(v + bias);
          const int brow = mt * 32 + (r & 3) + ((r >> 2) << 3) + (lh << 2);
          dst[(size_t)brow * HD + jc] = v;
          if (sq) sq[(size_t)brow * HD + jc] = v;
        }
    }
    __builtin_amdgcn_fence(__ATOMIC_RELEASE, "agent");
    __syncthreads();
    if (tid == 0)
      __hip_atomic_fetch_add(&prod[layer], 1u, __ATOMIC_RELEASE, __HIP_MEMORY_SCOPE_AGENT);
  }
}

// out[b][j] = lb[j] + sum_k h_last[b][k] * lw[j][k]  (+ eflag sentinel on out[0])
extern "C" __global__ void __launch_bounds__(512)
head_k(const float* __restrict__ ring, const float* __restrict__ lw,
       const float* __restrict__ lb, float* __restrict__ out,
       const uint* __restrict__ eflag) {
  __shared__ float hrow[HD];
  const int b = blockIdx.x;
  const int j = threadIdx.x;
  hrow[j] = ring[ringOff(LPP - 1, (TSTEPS - 1) & RMASK) + (size_t)b * HD + j];
  __syncthreads();
  const float* wrow = lw + (size_t)j * HD;
  float s = lb[j];
#pragma unroll 4
  for (int k = 0; k < HD; k += 4) {
    const float4 w = *(const float4*)(wrow + k);
    s += hrow[k] * w.x + hrow[k + 1] * w.y + hrow[k + 2] * w.z + hrow[k + 3] * w.w;
  }
  if (b == 0 && j == 0) s += (float)eflag[0];
  out[(size_t)b * HD + j] = s;
}

extern "C" void kernel_launch(void* const* d_in, const int* in_sizes, int n_in,
                              void* d_out, int out_size, void* d_ws, size_t ws_size,
                              hipStream_t stream) {
  const float* x   = (const float*)d_in[0];
  const float* Wih = (const float*)d_in[1];
  const float* Whh = (const float*)d_in[2];
  const float* bih = (const float*)d_in[3];
  const float* bhh = (const float*)d_in[4];
  const float* lw  = (const float*)d_in[5];
  const float* lb  = (const float*)d_in[6];
  float* out = (float*)d_out;

  const bool ok = n_in == 7 && in_sizes[0] == 4194304 && in_sizes[1] == 16777216 &&
                  in_sizes[2] == 16777216 && in_sizes[3] == 32768 && in_sizes[4] == 32768 &&
                  in_sizes[5] == 262144 && in_sizes[6] == 512 && out_size == 32768;
  const size_t ring_b = (size_t)LPP * RSLOT * 32768 * 4;  // 16.78 MB
  const size_t seq_b = (size_t)TSTEPS * 32768 * 4;        // 16.78 MB
  const size_t need = 4096 + ring_b + seq_b;
  if (!ok || ws_size < need) {
    sent_k<<<128, 256, 0, stream>>>(out, ok ? (100.0f + (float)(ws_size >> 20)) : 900.0f,
                                    out_size);
    return;
  }

  uint* prod = (uint*)d_ws;
  uint* cons = prod + 64;
  uint* eflag = cons + 64;
  float* ring = (float*)((char*)d_ws + 4096);
  float* seqbuf = (float*)((char*)d_ws + 4096 + ring_b);

  hipFuncSetAttribute((const void*)rnn_pipe,
                      hipFuncAttributeMaxDynamicSharedMemorySize, 131072);
  const size_t wl = (size_t)LPP * HD * HD;  // weight floats per pass
  // pass 1: layers 0..31, input x, top layer -> seqbuf
  hipMemsetAsync(d_ws, 0, 4096, stream);
  rnn_pipe<<<256, 256, 131072, stream>>>(x, Wih, Whh, bih, bhh, ring, seqbuf,
                                         prod, cons, eflag);
  // pass 2: layers 32..63, input seqbuf, no seq output
  hipMemsetAsync(d_ws, 0, 2048, stream);  // prod/cons only; keep eflag? (eflag at 512B) - rezero flags
  rnn_pipe<<<256, 256, 131072, stream>>>(seqbuf, Wih + wl, Whh + wl,
                                         bih + LPP * HD, bhh + LPP * HD, ring, nullptr,
                                         prod, cons, eflag);
  head_k<<<64, 512, 0, stream>>>(ring, lw, lb, out, eflag);
}

// Round 7
// 9256.440 us; speedup vs baseline: 19.8802x; 2.0433x over previous
//
#include <hip/hip_runtime.h>

#define TSTEPS 128
#define NB 64
#define HD 512
#define LPP 32        // layers per pass (2 passes)
#define RSLOT 4
#define RMASK 3
#define SPIN_CAP 120000

typedef unsigned int uint;
typedef unsigned long long ull;
typedef _Float16 f16;
typedef _Float16 f16x8 __attribute__((ext_vector_type(8)));
typedef float f32x16 __attribute__((ext_vector_type(16)));

// ring slot: [layer 0..31][slot 0..3] of 64x512 fp32 (32768 floats = 128KB)
__device__ __forceinline__ size_t ringOff(int layer, int slot) {
  return ((size_t)(layer * RSLOT + slot)) << 15;
}

__device__ __forceinline__ ull ald64(const void* p) {
  return __hip_atomic_load((const ull*)p, __ATOMIC_RELAXED, __HIP_MEMORY_SCOPE_AGENT);
}
__device__ __forceinline__ void ast32(float* p, float v) {
  __hip_atomic_store((uint*)p, __builtin_bit_cast(uint, v), __ATOMIC_RELAXED,
                     __HIP_MEMORY_SCOPE_AGENT);
}

extern "C" __global__ void sent_k(float* out, float val, int n) {
  int i = blockIdx.x * 256 + threadIdx.x;
  if (i < n) out[i] = val;
}

// 32 layer-groups x 8 CUs. Per CU: 64 out-cols, M=64, K=1024.
// W f16 hi/lo resident in VGPRs. A staged per-half as f16 hi/lo in LDS, XOR-swizzled.
// 3-term MFMA (~fp23). Ring fp32, ALL ring traffic = relaxed agent atomics
// (L1/L2-bypass -> coherent at Infinity Cache, NO fences anywhere).
extern "C" __global__ void __launch_bounds__(256, 1)
rnn_pipe(const float* __restrict__ xin, const float* __restrict__ Wih,
         const float* __restrict__ Whh, const float* __restrict__ bih,
         const float* __restrict__ bhh, float* ring, float* seqout,
         uint* prod, uint* cons, uint* eflag) {
  extern __shared__ char smem[];  // A_hi @0 (64KB), A_lo @65536 (64KB); scr overlays @0
  const int tid = threadIdx.x;
  const int bid = blockIdx.x;
  const int slotid = ((bid & 7) << 5) | (bid >> 3);  // 32 consecutive slots per XCD
  const int layer = slotid >> 3;                     // 4 layers per XCD
  const int c8 = slotid & 7;                         // col-eighth (64 cols)
  const int wv = tid >> 6;
  const int lane = tid & 63;
  const int l31 = lane & 31;
  const int lh = lane >> 5;       // k-half within a 16-k MFMA step
  const int kh = wv >> 1;         // wave's 256-k slice of each half
  const int nh = wv & 1;          // col-half (32 cols)
  const int jc = c8 * 64 + nh * 32 + l31;

  // ---- weights -> VGPRs as f16 hi/lo (once) ----
  const float* wih_row = Wih + ((size_t)layer * HD + jc) * HD + kh * 256;
  const float* whh_row = Whh + ((size_t)layer * HD + jc) * HD + kh * 256;
  f16x8 WihH[16], WihL[16], WhhH[16], WhhL[16];
#pragma unroll
  for (int s = 0; s < 16; ++s) {
    const int k = s * 16 + lh * 8;
#pragma unroll
    for (int p = 0; p < 2; ++p) {
      const float* src = p ? (whh_row + k) : (wih_row + k);
      float4 f0 = *(const float4*)src;
      float4 f1 = *(const float4*)(src + 4);
      union { f16 h[8]; f16x8 v; } H, L;
      float c[8] = {f0.x, f0.y, f0.z, f0.w, f1.x, f1.y, f1.z, f1.w};
#pragma unroll
      for (int e = 0; e < 8; ++e) {
        f16 hv = (f16)c[e];
        H.h[e] = hv;
        L.h[e] = (f16)(c[e] - (float)hv);
      }
      if (p) { WhhH[s] = H.v; WhhL[s] = L.v; }
      else   { WihH[s] = H.v; WihL[s] = L.v; }
    }
  }
  const float bias = bih[layer * HD + jc] + bhh[layer * HD + jc];

  const int rswz = l31 << 4;      // full 32-slot XOR swizzle (rows are 1024B)
  const int rowoff0 = l31 * 1024;
  const int rowoff1 = (32 + l31) * 1024;
  const int khb = kh * 512;
  const int lh16 = lh * 16;

  int cap = SPIN_CAP;

#pragma unroll 1
  for (int t = 0; t < TSTEPS; ++t) {
    const int sT = t & RMASK;
    const int sP = (t - 1) & RMASK;
    // ---- waits (tid 0; relaxed polls — atomics bypass caches, always fresh) ----
    if (tid == 0) {
      uint code = 0;
      if (layer < LPP - 1 && t >= RSLOT) {
        const uint need = 8u * (uint)(t - RSLOT + 1);
        int sp = 0;
        while (__hip_atomic_load(&cons[layer], __ATOMIC_RELAXED, __HIP_MEMORY_SCOPE_AGENT) < need) {
          __builtin_amdgcn_s_sleep(2);
          if (++sp > cap) { code = 1000u + layer; break; }
        }
      }
      if (layer > 0) {
        const uint need = 8u * (uint)(t + 1);
        int sp = 0;
        while (__hip_atomic_load(&prod[layer - 1], __ATOMIC_RELAXED, __HIP_MEMORY_SCOPE_AGENT) < need) {
          __builtin_amdgcn_s_sleep(2);
          if (++sp > cap) { code = 3000u + layer; break; }
        }
      }
      if (t > 0) {
        const uint need = 8u * (uint)t;
        int sp = 0;
        while (__hip_atomic_load(&prod[layer], __ATOMIC_RELAXED, __HIP_MEMORY_SCOPE_AGENT) < need) {
          __builtin_amdgcn_s_sleep(2);
          if (++sp > cap) { code = 5000u + layer; break; }
        }
      }
      if (code) {
        __hip_atomic_fetch_max(eflag, code, __ATOMIC_RELAXED, __HIP_MEMORY_SCOPE_AGENT);
        cap = 2000;
      }
    }
    __syncthreads();

    f32x16 acc0 = {};
    f32x16 acc1 = {};

    // ---- stage a 512-K half into LDS as f16 hi/lo (swizzled) ----
    // mode 0: zeros; 1: regular float4 (read-only/kernel-boundary src); 2: ring atomics
    auto stage = [&](const float* src, int mode) {
#pragma unroll 4
      for (int i = 0; i < 32; ++i) {
        const int idx4 = tid + (i << 8);          // [0,8192)
        const int b = idx4 >> 7, k4 = idx4 & 127;
        float c[4] = {0.f, 0.f, 0.f, 0.f};
        if (mode == 1) {
          float4 v = ((const float4*)src)[(size_t)b * 128 + k4];
          c[0] = v.x; c[1] = v.y; c[2] = v.z; c[3] = v.w;
        } else if (mode == 2) {
          const char* sp = (const char*)(src + (size_t)b * HD + k4 * 4);
          ull lo = ald64(sp);
          ull hi = ald64(sp + 8);
          c[0] = __builtin_bit_cast(float, (uint)lo);
          c[1] = __builtin_bit_cast(float, (uint)(lo >> 32));
          c[2] = __builtin_bit_cast(float, (uint)hi);
          c[3] = __builtin_bit_cast(float, (uint)(hi >> 32));
        }
        union { f16 h[4]; ull u; } H, L;
#pragma unroll
        for (int e = 0; e < 4; ++e) {
          f16 hv = (f16)c[e];
          H.h[e] = hv;
          L.h[e] = (f16)(c[e] - (float)hv);
        }
        const int off = b * 1024 + ((k4 * 8) ^ ((b & 31) << 4));
        *(ull*)(smem + off) = H.u;
        *(ull*)(smem + 65536 + off) = L.u;
      }
    };
    // ---- 3-term MFMA over this wave's 256-K slice of the staged half ----
    auto compute = [&](const f16x8* WH, const f16x8* WL) {
#pragma unroll
      for (int s = 0; s < 16; ++s) {
        const int kb = khb + s * 32 + lh16;
#pragma unroll
        for (int mt = 0; mt < 2; ++mt) {
          const int off = (mt ? rowoff1 : rowoff0) + (kb ^ rswz);
          const f16x8 ah = *(const f16x8*)(smem + off);
          const f16x8 al = *(const f16x8*)(smem + 65536 + off);
          if (mt == 0) {
            acc0 = __builtin_amdgcn_mfma_f32_32x32x16_f16(ah, WH[s], acc0, 0, 0, 0);
            acc0 = __builtin_amdgcn_mfma_f32_32x32x16_f16(al, WH[s], acc0, 0, 0, 0);
            acc0 = __builtin_amdgcn_mfma_f32_32x32x16_f16(ah, WL[s], acc0, 0, 0, 0);
          } else {
            acc1 = __builtin_amdgcn_mfma_f32_32x32x16_f16(ah, WH[s], acc1, 0, 0, 0);
            acc1 = __builtin_amdgcn_mfma_f32_32x32x16_f16(al, WH[s], acc1, 0, 0, 0);
            acc1 = __builtin_amdgcn_mfma_f32_32x32x16_f16(ah, WL[s], acc1, 0, 0, 0);
          }
        }
      }
    };

    // half 1: x-path
    if (layer == 0) stage(xin + (size_t)t * 32768, 1);
    else            stage(ring + ringOff(layer - 1, sT), 2);
    __syncthreads();  // drains each wave's ring atomic loads (vmcnt) + LDS writes
    if (tid == 0 && layer > 0)
      __hip_atomic_fetch_add(&cons[layer - 1], 1u, __ATOMIC_RELAXED, __HIP_MEMORY_SCOPE_AGENT);
    compute(WihH, WihL);
    __syncthreads();
    // half 2: h-path
    if (t > 0) stage(ring + ringOff(layer, sP), 2);
    else       stage(nullptr, 0);
    __syncthreads();
    compute(WhhH, WhhL);
    __syncthreads();

    // ---- cross-wave K-reduction (scratch overlays A_hi region) ----
    float* scr = (float*)smem;
    if (kh == 1) {
#pragma unroll
      for (int mt = 0; mt < 2; ++mt)
#pragma unroll
        for (int r = 0; r < 16; ++r)
          scr[(nh * 2 + mt) * 1024 + lane * 16 + r] = (mt ? acc1 : acc0)[r];
    }
    __syncthreads();
    if (kh == 0) {
      float* dst = ring + ringOff(layer, sT);
      float* sq = (seqout && layer == LPP - 1) ? seqout + (size_t)t * 32768 : nullptr;
#pragma unroll
      for (int mt = 0; mt < 2; ++mt)
#pragma unroll
        for (int r = 0; r < 16; ++r) {
          float v = (mt ? acc1 : acc0)[r] + scr[(nh * 2 + mt) * 1024 + lane * 16 + r];
          v = tanhf(v + bias);
          const int brow = mt * 32 + (r & 3) + ((r >> 2) << 3) + (lh << 2);
          ast32(&dst[(size_t)brow * HD + jc], v);   // coherence-point store
          if (sq) sq[(size_t)brow * HD + jc] = v;   // regular: kernel boundary covers
        }
    }
    __syncthreads();  // all waves' ring stores retired (vmcnt drained) before flag
    if (tid == 0)
      __hip_atomic_fetch_add(&prod[layer], 1u, __ATOMIC_RELAXED, __HIP_MEMORY_SCOPE_AGENT);
  }
}

// out[b][j] = lb[j] + sum_k h_last[b][k] * lw[j][k]  (+ eflag sentinel on out[0])
extern "C" __global__ void __launch_bounds__(512)
head_k(const float* __restrict__ ring, const float* __restrict__ lw,
       const float* __restrict__ lb, float* __restrict__ out,
       const uint* __restrict__ eflag) {
  __shared__ float hrow[HD];
  const int b = blockIdx.x;
  const int j = threadIdx.x;
  hrow[j] = ring[ringOff(LPP - 1, (TSTEPS - 1) & RMASK) + (size_t)b * HD + j];
  __syncthreads();
  const float* wrow = lw + (size_t)j * HD;
  float s = lb[j];
#pragma unroll 4
  for (int k = 0; k < HD; k += 4) {
    const float4 w = *(const float4*)(wrow + k);
    s += hrow[k] * w.x + hrow[k + 1] * w.y + hrow[k + 2] * w.z + hrow[k + 3] * w.w;
  }
  if (b == 0 && j == 0) s += (float)eflag[0];
  out[(size_t)b * HD + j] = s;
}

extern "C" void kernel_launch(void* const* d_in, const int* in_sizes, int n_in,
                              void* d_out, int out_size, void* d_ws, size_t ws_size,
                              hipStream_t stream) {
  const float* x   = (const float*)d_in[0];
  const float* Wih = (const float*)d_in[1];
  const float* Whh = (const float*)d_in[2];
  const float* bih = (const float*)d_in[3];
  const float* bhh = (const float*)d_in[4];
  const float* lw  = (const float*)d_in[5];
  const float* lb  = (const float*)d_in[6];
  float* out = (float*)d_out;

  const bool ok = n_in == 7 && in_sizes[0] == 4194304 && in_sizes[1] == 16777216 &&
                  in_sizes[2] == 16777216 && in_sizes[3] == 32768 && in_sizes[4] == 32768 &&
                  in_sizes[5] == 262144 && in_sizes[6] == 512 && out_size == 32768;
  const size_t ring_b = (size_t)LPP * RSLOT * 32768 * 4;  // 16.78 MB
  const size_t seq_b = (size_t)TSTEPS * 32768 * 4;        // 16.78 MB
  const size_t need = 4096 + ring_b + seq_b;
  if (!ok || ws_size < need) {
    sent_k<<<128, 256, 0, stream>>>(out, ok ? (100.0f + (float)(ws_size >> 20)) : 900.0f,
                                    out_size);
    return;
  }

  uint* prod = (uint*)d_ws;
  uint* cons = prod + 64;
  uint* eflag = cons + 64;
  float* ring = (float*)((char*)d_ws + 4096);
  float* seqbuf = (float*)((char*)d_ws + 4096 + ring_b);

  hipFuncSetAttribute((const void*)rnn_pipe,
                      hipFuncAttributeMaxDynamicSharedMemorySize, 131072);
  const size_t wl = (size_t)LPP * HD * HD;  // weight floats per pass
  // pass 1: layers 0..31, input x, top layer -> seqbuf
  hipMemsetAsync(d_ws, 0, 4096, stream);
  rnn_pipe<<<256, 256, 131072, stream>>>(x, Wih, Whh, bih, bhh, ring, seqbuf,
                                         prod, cons, eflag);
  // pass 2: layers 32..63, input seqbuf (kernel-boundary visible), no seq output
  hipMemsetAsync(d_ws, 0, 512, stream);  // re-zero prod/cons, preserve eflag
  rnn_pipe<<<256, 256, 131072, stream>>>(seqbuf, Wih + wl, Whh + wl,
                                         bih + LPP * HD, bhh + LPP * HD, ring, nullptr,
                                         prod, cons, eflag);
  head_k<<<64, 512, 0, stream>>>(ring, lw, lb, out, eflag);
}

// Round 12
// 5790.524 us; speedup vs baseline: 31.7794x; 1.5985x over previous
//
#include <hip/hip_runtime.h>

#define TSTEPS 128
#define HD 512
#define LPP 32        // layers per pass (2 passes)
#define RSLOT 4
#define RMASK 3
#define SPIN_CAP 150000
#define SLOT_B 131072 // slot = verbatim LDS image: hi plane 64KB @0, lo plane 64KB @65536
                      // element (b,k): byte b*1024 + ((k>>2)*8 ^ ((b&31)<<4)) + (k&3)*2

typedef unsigned int uint;
typedef unsigned short u16;
typedef unsigned long long ull;
typedef _Float16 f16;
typedef _Float16 f16x8 __attribute__((ext_vector_type(8)));
typedef float f32x16 __attribute__((ext_vector_type(16)));
typedef uint u32x4 __attribute__((ext_vector_type(4)));

__device__ __forceinline__ size_t ringOff(int layer, int slot) {
  return (size_t)(layer * RSLOT + slot) * SLOT_B;
}

// coherent (bypass L1/L2 -> coherence point) 16B load/store, flat VGPR address
__device__ __forceinline__ u32x4 gl16(const void* p) {
  u32x4 r;
  asm volatile("global_load_dwordx4 %0, %1, off sc0 sc1" : "=v"(r) : "v"(p));
  return r;
}
__device__ __forceinline__ void gs16(void* p, u32x4 d) {
  asm volatile("global_store_dwordx4 %0, %1, off sc0 sc1" ::"v"(p), "v"(d)
               : "memory");
}
#define VMWAIT(N)                                       \
  asm volatile("s_waitcnt vmcnt(" #N ")" ::: "memory"); \
  __builtin_amdgcn_sched_barrier(0)

#define POLL(PTR, NEED, CODE)                                                               \
  {                                                                                         \
    int sp = 0;                                                                             \
    while (__hip_atomic_load((PTR), __ATOMIC_RELAXED, __HIP_MEMORY_SCOPE_AGENT) < (NEED)) { \
      __builtin_amdgcn_s_sleep(1);                                                          \
      if (++sp > cap) {                                                                     \
        __hip_atomic_fetch_max(eflag, (uint)(CODE), __ATOMIC_RELAXED,                       \
                               __HIP_MEMORY_SCOPE_AGENT);                                   \
        cap = 2000;                                                                         \
        break;                                                                              \
      }                                                                                     \
    }                                                                                       \
  }

extern "C" __global__ void sent_k(float* out, float val, int n) {
  int i = blockIdx.x * 256 + threadIdx.x;
  if (i < n) out[i] = val;
}

// x fp32 [t][64][512] -> image slots xhl[t] (hi/lo f16, swizzled LDS image format)
extern "C" __global__ void __launch_bounds__(256)
xprep(const float* __restrict__ x, char* __restrict__ xhl) {
  const int t = blockIdx.x, tid = threadIdx.x;
#pragma unroll 4
  for (int i = 0; i < 32; ++i) {
    const int g = i * 256 + tid;          // group of 4 elements
    const int b = g >> 7, k4 = g & 127;
    const float4 v = *(const float4*)(x + (size_t)t * 32768 + b * 512 + k4 * 4);
    float c[4] = {v.x, v.y, v.z, v.w};
    union { f16 h[4]; ull u; } H, L;
#pragma unroll
    for (int e = 0; e < 4; ++e) {
      f16 hv = (f16)c[e];
      H.h[e] = hv;
      L.h[e] = (f16)(c[e] - (float)hv);
    }
    const int off = b * 1024 + ((k4 * 8) ^ ((b & 31) << 4));
    *(ull*)(xhl + (size_t)t * SLOT_B + off) = H.u;
    *(ull*)(xhl + (size_t)t * SLOT_B + 65536 + off) = L.u;
  }
}

// 32 layer-groups x 8 CUs. Per CU: 64 out-cols, M=64, K=1024.
// Wave = (kh: 256-k slice, nh: 32-col half); W hi/lo f16 in regs (round-7 layout).
// A staged by verbatim 128KB image copy ring->LDS (pipelined, zero VALU).
// 3-term MFMA (~fp23); scr reduce + tanh + image-chunk stores.
extern "C" __global__ void __launch_bounds__(256, 1)
rnn_pipe(const char* __restrict__ xsrc, const float* __restrict__ Wih,
         const float* __restrict__ Whh, const float* __restrict__ bih,
         const float* __restrict__ bhh, char* ring, char* seqout,
         uint* prod, uint* cons, uint* eflag) {
  extern __shared__ char smem[];  // stage image 128KB; post-compute: scr 16KB @0, out-tile 16KB @16384
  const int tid = threadIdx.x;
  const int bid = blockIdx.x;
  const int slotid = ((bid & 7) << 5) | (bid >> 3);  // 4 layers per XCD
  const int layer = slotid >> 3;
  const int c8 = slotid & 7;      // col-eighth (64 cols)
  const int wv = tid >> 6;
  const int lane = tid & 63;
  const int l31 = lane & 31;
  const int lh = lane >> 5;       // k-half within a 16-k MFMA step
  const int kh = wv >> 1;         // wave's 256-k slice of each half
  const int nh = wv & 1;          // col-half (32 cols)
  const int jc = c8 * 64 + nh * 32 + l31;

  // ---- weights -> regs as f16 hi/lo (once); wave: 32 cols x 256 k of Wih AND Whh ----
  const float* wih_row = Wih + ((size_t)layer * HD + jc) * HD + kh * 256;
  const float* whh_row = Whh + ((size_t)layer * HD + jc) * HD + kh * 256;
  f16x8 WihH[16], WihL[16], WhhH[16], WhhL[16];
#pragma unroll
  for (int s = 0; s < 16; ++s) {
    const int k = s * 16 + lh * 8;
#pragma unroll
    for (int p = 0; p < 2; ++p) {
      const float* src = p ? (whh_row + k) : (wih_row + k);
      float4 f0 = *(const float4*)src;
      float4 f1 = *(const float4*)(src + 4);
      union { f16 h[8]; f16x8 v; } H, L;
      float c[8] = {f0.x, f0.y, f0.z, f0.w, f1.x, f1.y, f1.z, f1.w};
#pragma unroll
      for (int e = 0; e < 8; ++e) {
        f16 hv = (f16)c[e];
        H.h[e] = hv;
        L.h[e] = (f16)(c[e] - (float)hv);
      }
      if (p) { WhhH[s] = H.v; WhhL[s] = L.v; }
      else   { WihH[s] = H.v; WihL[s] = L.v; }
    }
  }
  const float biasreg = bih[layer * HD + jc] + bhh[layer * HD + jc];

  const int rswz = l31 << 4;
  const int rowoff0 = l31 * 1024;
  const int rowoff1 = (32 + l31) * 1024;
  const int khb = kh * 512;       // byte base of this wave's k-slice within a half
  const int lh16 = lh * 16;

  int cap = SPIN_CAP;

#pragma unroll 1
  for (int t = 0; t < TSTEPS; ++t) {
    const int sT = t & RMASK;
    const int sP = (t - 1) & RMASK;
    // ---- waits: three wave-leader threads poll concurrently ----
    if (tid == 0 && layer < LPP - 1 && t >= RSLOT)
      POLL(&cons[layer], 8u * (uint)(t - RSLOT + 1), 1000u + layer);
    if (tid == 64 && layer > 0)
      POLL(&prod[layer - 1], 8u * (uint)(t + 1), 3000u + layer);
    if (tid == 128 && t > 0)
      POLL(&prod[layer], 8u * (uint)t, 5000u + layer);
    __syncthreads();

    f32x16 acc0 = {};
    f32x16 acc1 = {};

    // ---- stage: verbatim 128KB image copy src -> LDS, 16-deep pipelined ----
    auto stagecopy = [&](const char* src) {
      const char* sb64 = src + tid * 16;
      char* db64 = smem + tid * 16;
      u32x4 sreg[4][4];
#define SIS(B)                                     \
  if ((B) < 8) {                                   \
    const char* pb_ = sb64 + (B) * 16384;          \
    sreg[(B) & 3][0] = gl16(pb_);                  \
    sreg[(B) & 3][1] = gl16(pb_ + 4096);           \
    sreg[(B) & 3][2] = gl16(pb_ + 8192);           \
    sreg[(B) & 3][3] = gl16(pb_ + 12288);          \
  }
#define SWR(B)                                     \
  {                                                \
    char* qb_ = db64 + (B) * 16384;                \
    *(u32x4*)(qb_) = sreg[(B) & 3][0];             \
    *(u32x4*)(qb_ + 4096) = sreg[(B) & 3][1];      \
    *(u32x4*)(qb_ + 8192) = sreg[(B) & 3][2];      \
    *(u32x4*)(qb_ + 12288) = sreg[(B) & 3][3];     \
  }
      SIS(0); SIS(1); SIS(2); SIS(3);
      VMWAIT(12); SWR(0); SIS(4);
      VMWAIT(12); SWR(1); SIS(5);
      VMWAIT(12); SWR(2); SIS(6);
      VMWAIT(12); SWR(3); SIS(7);
      VMWAIT(12); SWR(4);
      VMWAIT(8);  SWR(5);
      VMWAIT(4);  SWR(6);
      VMWAIT(0);  SWR(7);
#undef SIS
#undef SWR
    };
    // ---- 3-term MFMA over this wave's 256-k slice of the staged half (round-7 code) ----
    auto compute = [&](const f16x8* WH, const f16x8* WL) {
#pragma unroll
      for (int s = 0; s < 16; ++s) {
        const int kb = khb + s * 32 + lh16;
#pragma unroll
        for (int mt = 0; mt < 2; ++mt) {
          const int off = (mt ? rowoff1 : rowoff0) + (kb ^ rswz);
          const f16x8 ah = *(const f16x8*)(smem + off);
          const f16x8 al = *(const f16x8*)(smem + 65536 + off);
          if (mt == 0) {
            acc0 = __builtin_amdgcn_mfma_f32_32x32x16_f16(ah, WH[s], acc0, 0, 0, 0);
            acc0 = __builtin_amdgcn_mfma_f32_32x32x16_f16(al, WH[s], acc0, 0, 0, 0);
            acc0 = __builtin_amdgcn_mfma_f32_32x32x16_f16(ah, WL[s], acc0, 0, 0, 0);
          } else {
            acc1 = __builtin_amdgcn_mfma_f32_32x32x16_f16(ah, WH[s], acc1, 0, 0, 0);
            acc1 = __builtin_amdgcn_mfma_f32_32x32x16_f16(al, WH[s], acc1, 0, 0, 0);
            acc1 = __builtin_amdgcn_mfma_f32_32x32x16_f16(ah, WL[s], acc1, 0, 0, 0);
          }
        }
      }
    };

    // half 1: x-path (prev-layer slot or x image)
    stagecopy(layer == 0 ? xsrc + (size_t)t * SLOT_B : ring + ringOff(layer - 1, sT));
    __syncthreads();
    if (tid == 0 && layer > 0)
      __hip_atomic_fetch_add(&cons[layer - 1], 1u, __ATOMIC_RELAXED, __HIP_MEMORY_SCOPE_AGENT);
    compute(WihH, WihL);
    __syncthreads();
    // half 2: h-path (own-layer slot t-1 or zeros)
    if (t > 0) {
      stagecopy(ring + ringOff(layer, sP));
    } else {
      const u32x4 z = {0, 0, 0, 0};
#pragma unroll
      for (int i = 0; i < 32; ++i) *(u32x4*)(smem + tid * 16 + i * 4096) = z;
    }
    __syncthreads();
    compute(WhhH, WhhL);
    __syncthreads();

    // ---- cross-wave K-reduction (round-7 scheme; scr 16KB overlays stage @0) ----
    float* scr = (float*)smem;
    if (kh == 1) {
#pragma unroll
      for (int mt = 0; mt < 2; ++mt)
#pragma unroll
        for (int r = 0; r < 16; ++r)
          scr[(nh * 2 + mt) * 1024 + lane * 16 + r] = (mt ? acc1 : acc0)[r];
    }
    __syncthreads();
    if (kh == 0) {
      // out-tile (plain layout) @16384: hi [64][64 f16] 8KB, lo @+8192
      const int lcol = nh * 32 + l31;
#pragma unroll
      for (int mt = 0; mt < 2; ++mt)
#pragma unroll
        for (int r = 0; r < 16; ++r) {
          float v = (mt ? acc1 : acc0)[r] + scr[(nh * 2 + mt) * 1024 + lane * 16 + r];
          v = tanhf(v + biasreg);
          const f16 hv = (f16)v;
          const f16 lv = (f16)(v - (float)hv);
          const int row = mt * 32 + 4 * lh + (r & 3) + 8 * (r >> 2);
          *(u16*)(smem + 16384 + row * 128 + lcol * 2) = __builtin_bit_cast(u16, hv);
          *(u16*)(smem + 24576 + row * 128 + lcol * 2) = __builtin_bit_cast(u16, lv);
        }
    }
    __syncthreads();

    // ---- store out-tile into slot image: 1024 chunks of 16B, 4 per thread ----
    {
      char* slotdst = ring + ringOff(layer, sT);
      const bool sq = (seqout != nullptr) && (layer == LPP - 1);
#pragma unroll
      for (int i = 0; i < 4; ++i) {
        const int c = tid * 4 + i;
        const int plane = c >> 9, b = (c >> 3) & 63, blk = c & 7;
        const u32x4 d = *(const u32x4*)(smem + 16384 + plane * 8192 + b * 128 + blk * 16);
        const int doff = plane * 65536 + b * 1024 + ((c8 * 128 + blk * 16) ^ ((b & 31) << 4));
        gs16(slotdst + doff, d);
        if (sq) gs16(seqout + (size_t)t * SLOT_B + doff, d);
      }
    }
    VMWAIT(0);
    __syncthreads();
    if (tid == 0)
      __hip_atomic_fetch_add(&prod[layer], 1u, __ATOMIC_RELAXED, __HIP_MEMORY_SCOPE_AGENT);
  }
}

// out[b][j] = lb[j] + sum_k (hi+lo)[b][k] * lw[j][k]  (+ eflag sentinel on out[0])
extern "C" __global__ void __launch_bounds__(512)
head_k(const char* __restrict__ ring, const float* __restrict__ lw,
       const float* __restrict__ lb, float* __restrict__ out,
       const uint* __restrict__ eflag) {
  __shared__ float hrow[HD];
  const int b = blockIdx.x;
  const int j = threadIdx.x;
  const char* slot = ring + ringOff(LPP - 1, (TSTEPS - 1) & RMASK);
  const int off = b * 1024 + (((j >> 2) * 8) ^ ((b & 31) << 4)) + (j & 3) * 2;
  const u16 hb = *(const u16*)(slot + off);
  const u16 lo = *(const u16*)(slot + 65536 + off);
  hrow[j] = (float)__builtin_bit_cast(f16, hb) + (float)__builtin_bit_cast(f16, lo);
  __syncthreads();
  const float* wrow = lw + (size_t)j * HD;
  float s = lb[j];
#pragma unroll 4
  for (int k = 0; k < HD; k += 4) {
    const float4 w = *(const float4*)(wrow + k);
    s += hrow[k] * w.x + hrow[k + 1] * w.y + hrow[k + 2] * w.z + hrow[k + 3] * w.w;
  }
  if (b == 0 && j == 0) s += (float)eflag[0];
  out[(size_t)b * HD + j] = s;
}

extern "C" void kernel_launch(void* const* d_in, const int* in_sizes, int n_in,
                              void* d_out, int out_size, void* d_ws, size_t ws_size,
                              hipStream_t stream) {
  const float* x   = (const float*)d_in[0];
  const float* Wih = (const float*)d_in[1];
  const float* Whh = (const float*)d_in[2];
  const float* bih = (const float*)d_in[3];
  const float* bhh = (const float*)d_in[4];
  const float* lw  = (const float*)d_in[5];
  const float* lb  = (const float*)d_in[6];
  float* out = (float*)d_out;

  const bool ok = n_in == 7 && in_sizes[0] == 4194304 && in_sizes[1] == 16777216 &&
                  in_sizes[2] == 16777216 && in_sizes[3] == 32768 && in_sizes[4] == 32768 &&
                  in_sizes[5] == 262144 && in_sizes[6] == 512 && out_size == 32768;
  const size_t ring_b = (size_t)LPP * RSLOT * SLOT_B;   // 16.78 MB
  const size_t seq_b  = (size_t)TSTEPS * SLOT_B;        // 16.78 MB
  const size_t xhl_b  = (size_t)TSTEPS * SLOT_B;        // 16.78 MB
  const size_t need = 4096 + ring_b + seq_b + xhl_b;    // ~50.3 MB
  if (!ok || ws_size < need) {
    sent_k<<<128, 256, 0, stream>>>(out, ok ? (100.0f + (float)(ws_size >> 20)) : 900.0f,
                                    out_size);
    return;
  }

  uint* prod = (uint*)d_ws;                       // 64 x u32
  uint* cons = (uint*)((char*)d_ws + 256);        // 64 x u32
  uint* eflag = (uint*)((char*)d_ws + 512);       // survives inter-pass re-zero
  char* ring   = (char*)d_ws + 4096;
  char* seqbuf = ring + ring_b;
  char* xhl    = seqbuf + seq_b;

  (void)hipFuncSetAttribute((const void*)rnn_pipe,
                            hipFuncAttributeMaxDynamicSharedMemorySize, 131072);
  xprep<<<128, 256, 0, stream>>>(x, xhl);
  const size_t wl = (size_t)LPP * HD * HD;
  // pass 1: layers 0..31, x from xhl, top layer also -> seqbuf
  (void)hipMemsetAsync(d_ws, 0, 4096, stream);
  rnn_pipe<<<256, 256, 131072, stream>>>(xhl, Wih, Whh, bih, bhh, ring, seqbuf,
                                         prod, cons, eflag);
  // pass 2: layers 32..63, x from seqbuf
  (void)hipMemsetAsync(d_ws, 0, 512, stream);  // re-zero prod/cons, keep eflag
  rnn_pipe<<<256, 256, 131072, stream>>>(seqbuf, Wih + wl, Whh + wl,
                                         bih + LPP * HD, bhh + LPP * HD, ring, nullptr,
                                         prod, cons, eflag);
  head_k<<<64, 512, 0, stream>>>(ring, lw, lb, out, eflag);
}